// Round 20
// baseline (236.331 us; speedup 1.0000x reference)
//
#include <hip/hip_runtime.h>
#include <hip/hip_fp16.h>
#include <math.h>

#define T_DIM 2048
#define TP_DIM 2056                  // padded t rows: tp = t + 4, 4 pad each side
#define K_DIM 17
#define HID   64
#define B_DIM 32

typedef short s16x8 __attribute__((ext_vector_type(8)));
typedef unsigned u32x2 __attribute__((ext_vector_type(2)));
typedef float f32x4 __attribute__((ext_vector_type(4)));
typedef _Float16 f16x2 __attribute__((ext_vector_type(2)));

__device__ __forceinline__ unsigned pkh(float lo, float hi) {
    return __builtin_bit_cast(unsigned, __builtin_amdgcn_cvt_pkrtz(lo, hi));
}
__device__ __forceinline__ f16x2 u2h(unsigned v) {
    return __builtin_bit_cast(f16x2, v);
}
__device__ __forceinline__ unsigned h2u(f16x2 v) {
    return __builtin_bit_cast(unsigned, v);
}
__device__ __forceinline__ short f2h(float f) {          // cold path
    _Float16 h = (_Float16)f;
    return __builtin_bit_cast(short, h);
}

// COCO skeleton sparsity: column-v nonzeros of adj (incl. self).
static constexpr int NBR_PTR[18] = {0,3,6,9,11,13,17,21,24,27,29,31,34,37,40,43,45,47};
static constexpr int NBR_K[47] = {
    0,1,2,  0,1,3,  0,2,4,  1,3,  2,4,
    5,6,7,11,  5,6,8,12,  5,7,9,  6,8,10,  7,9,  8,10,
    5,11,13,  6,12,14,  11,13,15,  12,14,16,  13,15,  14,16 };
__device__ const int d_NBR_PTR[18] = {0,3,6,9,11,13,17,21,24,27,29,31,34,37,40,43,45,47};
__device__ const int d_NBR_K[47] = {
    0,1,2,  0,1,3,  0,2,4,  1,3,  2,4,
    5,6,7,11,  5,6,8,12,  5,7,9,  6,8,10,  7,9,  8,10,
    5,11,13,  6,12,14,  11,13,15,  12,14,16,  13,15,  14,16 };

// ---------------------------------------------------------------------------
// Fold GCN channel-mix into temporal conv weights (f16).
//   effT0[o][k32]; effT12[blk][o][dt*64+c] for blocks 2,3.
// ---------------------------------------------------------------------------
__global__ void fold_weights_kernel(
    const float* __restrict__ gw0, const float* __restrict__ gw1,
    const float* __restrict__ gw2, const float* __restrict__ tcn,
    const float* __restrict__ bns, const float* __restrict__ bnb,
    const float* __restrict__ bnm, const float* __restrict__ bnv,
    short* __restrict__ effT0, short* __restrict__ effT12,
    float* __restrict__ bnc)
{
    int tid = blockIdx.x * blockDim.x + threadIdx.x;
    int stride = gridDim.x * blockDim.x;
    for (int idx = tid; idx < 2048; idx += stride) {
        int o = idx >> 5, k = idx & 31, dt = k >> 3, cin = k & 7;
        float s = 0.f;
        if (dt < 3 && cin < 3)
            for (int m = 0; m < 64; m++)
                s += gw0[cin * 64 + m] * tcn[(o * 64 + m) * 3 + dt];
        effT0[idx] = f2h(s);
    }
    for (int idx = tid; idx < 24576; idx += stride) {
        int blk = idx / 12288;
        int r = idx - blk * 12288;
        int o = r / 192, k = r - o * 192, dt = k >> 6, c = k & 63;
        const float* gw = blk ? gw2 : gw1;
        const float* tw = tcn + (size_t)(blk + 1) * 64 * 64 * 3;
        float s = 0.f;
        for (int m = 0; m < 64; m++)
            s += gw[c * 64 + m] * tw[(o * 64 + m) * 3 + dt];
        effT12[idx] = f2h(s);
    }
    for (int i = tid; i < 192; i += stride) {
        float inv = bns[i] * rsqrtf(bnv[i] + 1e-5f);
        bnc[i] = inv;
        bnc[192 + i] = bnb[i] - bnm[i] * inv;
    }
}

// ---------------------------------------------------------------------------
// Premix v2: WG = (b, 64 tp-rows).  The 64x51 x-block is CONTIGUOUS in x ->
// stage with coalesced b32 loads (validity = flat index range, no division),
// then gather the graph premix from LDS.  xg pitch 52 floats.
// ---------------------------------------------------------------------------
__global__ __launch_bounds__(256) void premix_kernel(
    const float* __restrict__ x, const float* __restrict__ adj,
    float* __restrict__ xg)
{
    __shared__ float xs[64 * 51];        // 13056 B
    __shared__ float adj_s[289];
    const int tid = threadIdx.x;
    const int b = blockIdx.y;
    const int tp0 = blockIdx.x * 64;

    for (int i = tid; i < 289; i += 256) adj_s[i] = adj[i];
    {   // stage x rows t = tp0-4 .. tp0+59 (contiguous), zero outside [0,T)
        const int t_lo = tp0 - 4;
        const int lo_i = (t_lo < 0) ? (-t_lo) * 51 : 0;
        int hr = T_DIM - t_lo;
        const int hi_i = (hr >= 64) ? 3264 : (hr < 0 ? 0 : hr * 51);
        const float* xb = x + ((size_t)b * T_DIM + t_lo) * 51;
        for (int i = tid; i < 3264; i += 256)
            xs[i] = (i >= lo_i && i < hi_i) ? xb[i] : 0.f;
    }
    __syncthreads();

    for (int it = tid; it < 1088; it += 256) {
        const int row = it / 17, j = it - row * 17;
        const int tp = tp0 + row;
        if (tp >= TP_DIM) continue;
        const int t = tp - 4;
        float a0 = 0.f, a1 = 0.f, a2 = 0.f;
        if (t >= 0 && t < T_DIM) {
            const float* xp = &xs[row * 51];
            const int p0 = d_NBR_PTR[j], p1 = d_NBR_PTR[j + 1];
            for (int e = p0; e < p1; e++) {
                int k = d_NBR_K[e];
                float w = adj_s[k * 17 + j];
                a0 += w * xp[k * 3 + 0];
                a1 += w * xp[k * 3 + 1];
                a2 += w * xp[k * 3 + 2];
            }
        }
        float* op = xg + ((size_t)b * TP_DIM + tp) * 52 + j * 3;
        op[0] = a0; op[1] = a1; op[2] = a2;
    }
}

// ---------------------------------------------------------------------------
// Monolith: all 3 blocks + pool, activations never leave LDS (same as R19).
// ---------------------------------------------------------------------------
__global__ __launch_bounds__(256, 4) void stgcn_mono_kernel(
    const float* __restrict__ xg, const float* __restrict__ adj,
    const short* __restrict__ effT0, const short* __restrict__ effT12,
    const float* __restrict__ bnc, float* __restrict__ part, int b0)
{
    __shared__ unsigned adj_h[289];
    __shared__ __align__(16) float xtg[16 * 52];       // 3328 B (aliased later)
    __shared__ __align__(16) short ybuf[238 * 72];     // 34272 B

    float* prm = (float*)xtg;            // [8][64] pool partials (xtg dead)
    float* pr1 = (float*)xtg + 512;      // [64] GEMM3 pool

    const int tid = threadIdx.x;
    const int b = blockIdx.y;
    const int t0 = blockIdx.x * 8;
    const int lane = tid & 63, wave = tid >> 6;
    const int col = lane & 15, kgrp = lane >> 4;

    for (int i = tid; i < 289; i += 256) {
        float w = adj[i];
        adj_h[i] = pkh(w, w);
    }
    {   // branch-free coalesced stage: 16 rows x 52 floats = 208 float4
        const float4* src = (const float4*)(xg + ((size_t)b * TP_DIM + t0) * 52);
        float4* dst = (float4*)xtg;
        for (int i = tid; i < 208; i += 256) dst[i] = src[i];
    }
    s16x8 af1 = *(const s16x8*)(effT0 + (wave * 16 + col) * 32 + kgrp * 8);
    s16x8 af2[6];
    #pragma unroll
    for (int kk = 0; kk < 6; kk++)
        af2[kk] = *(const s16x8*)(effT12 +
            (wave * 16 + col) * 192 + kk * 32 + kgrp * 8);
    __syncthreads();

    // ---- GEMM1: 238 rows (15 tiles), K=32; BN+ReLU epilogue -> y1 ----
    {
        f32x4 inv4 = *(const f32x4*)&bnc[wave * 16 + kgrp * 4];
        f32x4 sh4  = *(const f32x4*)&bnc[192 + wave * 16 + kgrp * 4];
        for (int tile = 0; tile < 15; tile++) {
            const int r = tile * 16 + col;
            const int me = r < 238 ? r : 237;
            const int s = (me * 241) >> 12;     // me/17 for me<256
            const int j = me - s * 17;
            int4 bz = {0, 0, 0, 0};
            if (kgrp < 3) {                      // dt = kgrp; x time = t0-4+s+dt
                const float* xp = &xtg[(s + kgrp) * 52 + j * 3];
                bz.x = (int)pkh(xp[0], xp[1]);
                bz.y = (int)pkh(xp[2], 0.f);
            }
            s16x8 bfr = __builtin_bit_cast(s16x8, bz);
            f32x4 acc = __builtin_amdgcn_mfma_f32_16x16x32_f16(
                af1, bfr, (f32x4){0.f, 0.f, 0.f, 0.f}, 0, 0, 0);
            const int t = t0 - 3 + s;
            const bool valid = (t >= 0) && (t < T_DIM);
            if (r < 238) {
                float v0 = valid ? fmaxf(acc[0] * inv4[0] + sh4[0], 0.f) : 0.f;
                float v1 = valid ? fmaxf(acc[1] * inv4[1] + sh4[1], 0.f) : 0.f;
                float v2 = valid ? fmaxf(acc[2] * inv4[2] + sh4[2], 0.f) : 0.f;
                float v3 = valid ? fmaxf(acc[3] * inv4[3] + sh4[3], 0.f) : 0.f;
                u32x2 st; st[0] = pkh(v0, v1); st[1] = pkh(v2, v3);
                *(u32x2*)&ybuf[r * 72 + wave * 16 + kgrp * 4] = st;
            }
        }
    }
    __syncthreads();

    // ---- residual preload: y1 rows (tl+1)*17+v for items (tl, o-pair) ----
    const int tl0 = tid >> 5, oq = tid & 31, o0 = oq * 2;
    unsigned rv[2][17];
    #pragma unroll
    for (int v = 0; v < 17; v++)
        rv[0][v] = *(const unsigned*)&ybuf[((tl0 + 1) * 17 + v) * 72 + o0];
    if (tid < 128) {
        #pragma unroll
        for (int v = 0; v < 17; v++)
            rv[1][v] = *(const unsigned*)&ybuf[((tl0 + 9) * 17 + v) * 72 + o0];
    }

    // ---- GEMM2 pass1: tiles 0..6 (rows 0..111; reads ybuf rows 0..145) ----
    f32x4 accA[7];
    #pragma unroll
    for (int t2 = 0; t2 < 7; t2++) accA[t2] = (f32x4){0.f, 0.f, 0.f, 0.f};
    #pragma unroll
    for (int kk = 0; kk < 6; kk++) {
        #pragma unroll
        for (int t2 = 0; t2 < 7; t2++) {
            const int r = t2 * 16 + col;
            s16x8 bfr = *(const s16x8*)&ybuf[
                (r + 17 * (kk >> 1)) * 72 + (kk & 1) * 32 + kgrp * 8];
            accA[t2] = __builtin_amdgcn_mfma_f32_16x16x32_f16(
                af2[kk], bfr, accA[t2], 0, 0, 0);
        }
    }
    __syncthreads();

    // ---- z2 write pass1 (rows 0..111) + GEMM2 pass2 (reads rows 112..237) ----
    #pragma unroll
    for (int t2 = 0; t2 < 7; t2++) {
        const int r = t2 * 16 + col;
        u32x2 st;
        st[0] = pkh(accA[t2][0], accA[t2][1]);
        st[1] = pkh(accA[t2][2], accA[t2][3]);
        *(u32x2*)&ybuf[r * 72 + wave * 16 + kgrp * 4] = st;
    }
    f32x4 accB[6];
    #pragma unroll
    for (int t2 = 0; t2 < 6; t2++) accB[t2] = (f32x4){0.f, 0.f, 0.f, 0.f};
    #pragma unroll
    for (int kk = 0; kk < 6; kk++) {
        #pragma unroll
        for (int t2 = 0; t2 < 6; t2++) {
            const int r = (t2 + 7) * 16 + col;
            const int me = r < 204 ? r : 203;
            s16x8 bfr = *(const s16x8*)&ybuf[
                (me + 17 * (kk >> 1)) * 72 + (kk & 1) * 32 + kgrp * 8];
            accB[t2] = __builtin_amdgcn_mfma_f32_16x16x32_f16(
                af2[kk], bfr, accB[t2], 0, 0, 0);
        }
    }
    __syncthreads();

    // ---- z2 write pass2 (rows 112..203) ----
    #pragma unroll
    for (int t2 = 0; t2 < 6; t2++) {
        const int r = (t2 + 7) * 16 + col;
        if (r < 204) {
            u32x2 st;
            st[0] = pkh(accB[t2][0], accB[t2][1]);
            st[1] = pkh(accB[t2][2], accB[t2][3]);
            *(u32x2*)&ybuf[r * 72 + wave * 16 + kgrp * 4] = st;
        }
    }
    __syncthreads();

    // ---- mix2 + pool + block3 premix, in-place (rows tl*17+*) ----
    {
        const f16x2 inv2 = u2h(pkh(bnc[64 + o0], bnc[64 + o0 + 1]));
        const f16x2 sh2  = u2h(pkh(bnc[256 + o0], bnc[256 + o0 + 1]));
        const f16x2 zero = u2h(0u);
        #pragma unroll
        for (int it = 0; it < 2; it++) {
            const int tl = tl0 + it * 8;
            if (it == 1 && tid >= 128) break;     // tl would exceed 11
            const int t = t0 - 2 + tl;
            const bool valid = (t >= 0) && (t < T_DIM);
            f16x2 zk[17];
            #pragma unroll
            for (int k = 0; k < 17; k++)
                zk[k] = u2h(*(const unsigned*)&ybuf[(tl * 17 + k) * 72 + o0]);
            f16x2 y2v[17];
            f16x2 pool = zero;
            #pragma unroll
            for (int v = 0; v < 17; v++) {
                f16x2 g = zero;
                #pragma unroll
                for (int e = NBR_PTR[v]; e < NBR_PTR[v + 1]; e++) {
                    int k = NBR_K[e];
                    g = u2h(adj_h[k * 17 + v]) * zk[k] + g;
                }
                f16x2 val = __builtin_elementwise_max(g * inv2 + sh2, zero);
                val = val + u2h(rv[it][v]);
                if (!valid) val = zero;
                y2v[v] = val;
                pool = pool + val;
            }
            if (tl >= 2 && tl <= 9) {
                prm[(tl - 2) * 64 + o0]     = (float)pool[0];
                prm[(tl - 2) * 64 + o0 + 1] = (float)pool[1];
            }
            #pragma unroll
            for (int j = 0; j < 17; j++) {
                f16x2 gg = zero;
                #pragma unroll
                for (int e = NBR_PTR[j]; e < NBR_PTR[j + 1]; e++) {
                    int k = NBR_K[e];
                    gg = u2h(adj_h[k * 17 + j]) * y2v[k] + gg;
                }
                *(unsigned*)&ybuf[(tl * 17 + j) * 72 + o0] = h2u(gg);
            }
        }
    }
    __syncthreads();

    // ---- GEMM3: 136 rows (9 tiles), K=192, DIL=2 + BN/ReLU + pool ----
    {
        s16x8 af3[6];
        #pragma unroll
        for (int kk = 0; kk < 6; kk++)
            af3[kk] = *(const s16x8*)(effT12 + 12288 +
                (wave * 16 + col) * 192 + kk * 32 + kgrp * 8);
        const f32x4 inv4 = *(const f32x4*)&bnc[128 + wave * 16 + kgrp * 4];
        const f32x4 sh4  = *(const f32x4*)&bnc[320 + wave * 16 + kgrp * 4];
        float psum[4] = {0.f, 0.f, 0.f, 0.f};
        for (int t3 = 0; t3 < 9; t3++) {
            const int r = t3 * 16 + col;
            const int me = r < 136 ? r : 135;
            f32x4 acc = (f32x4){0.f, 0.f, 0.f, 0.f};
            #pragma unroll
            for (int kk = 0; kk < 6; kk++) {
                s16x8 bfr = *(const s16x8*)&ybuf[
                    (me + 34 * (kk >> 1)) * 72 + (kk & 1) * 32 + kgrp * 8];
                acc = __builtin_amdgcn_mfma_f32_16x16x32_f16(
                    af3[kk], bfr, acc, 0, 0, 0);
            }
            if (r < 136) {
                psum[0] += fmaxf(acc[0] * inv4[0] + sh4[0], 0.f);
                psum[1] += fmaxf(acc[1] * inv4[1] + sh4[1], 0.f);
                psum[2] += fmaxf(acc[2] * inv4[2] + sh4[2], 0.f);
                psum[3] += fmaxf(acc[3] * inv4[3] + sh4[3], 0.f);
            }
        }
        #pragma unroll
        for (int off = 1; off <= 8; off <<= 1) {
            psum[0] += __shfl_xor(psum[0], off);
            psum[1] += __shfl_xor(psum[1], off);
            psum[2] += __shfl_xor(psum[2], off);
            psum[3] += __shfl_xor(psum[3], off);
        }
        if (col == 0)
            *(f32x4*)&pr1[wave * 16 + kgrp * 4] =
                (f32x4){psum[0], psum[1], psum[2], psum[3]};
    }
    __syncthreads();
    if (tid < 64) {
        float s = pr1[tid];
        #pragma unroll
        for (int i = 0; i < 8; i++) s += prm[i * 64 + tid];
        part[((size_t)(b0 + b) * 256 + blockIdx.x) * 64 + tid] = s;
    }
}

// ---------------------------------------------------------------------------
// Sum 256 partials per (b,c) with 256 threads, mean, LayerNorm, FC.
// ---------------------------------------------------------------------------
__global__ __launch_bounds__(256) void finish_kernel(
    const float* __restrict__ part, const float* __restrict__ ln_s,
    const float* __restrict__ ln_b, const float* __restrict__ fc_w,
    const float* __restrict__ fc_b, float* __restrict__ out)
{
    __shared__ float red[4][64];
    __shared__ float ns[64];
    const int b = blockIdx.x;
    const int g = threadIdx.x >> 6, c = threadIdx.x & 63;
    float s = 0.f;
    for (int j = 0; j < 64; j++)
        s += part[((size_t)b * 256 + g * 64 + j) * 64 + c];
    red[g][c] = s;
    __syncthreads();
    if (threadIdx.x < 64) {
        float feat = (red[0][c] + red[1][c] + red[2][c] + red[3][c])
                   / (float)(T_DIM * K_DIM);
        float m = feat;
        #pragma unroll
        for (int off = 32; off > 0; off >>= 1) m += __shfl_down(m, off);
        m = __shfl(m, 0) / 64.f;
        float d = feat - m;
        float v = d * d;
        #pragma unroll
        for (int off = 32; off > 0; off >>= 1) v += __shfl_down(v, off);
        v = __shfl(v, 0) / 64.f;
        ns[c] = d * rsqrtf(v + 1e-5f) * ln_s[c] + ln_b[c];
    }
    __syncthreads();
    if (threadIdx.x < 10) {
        float o = fc_b[threadIdx.x];
        for (int i = 0; i < 64; i++) o += ns[i] * fc_w[i * 10 + threadIdx.x];
        out[b * 10 + threadIdx.x] = o;
    }
}

// ---------------------------------------------------------------------------
extern "C" void kernel_launch(void* const* d_in, const int* in_sizes, int n_in,
                              void* d_out, int out_size, void* d_ws, size_t ws_size,
                              hipStream_t stream)
{
    const float* kpts = (const float*)d_in[0];
    const float* adj  = (const float*)d_in[1];
    const float* gw0  = (const float*)d_in[2];
    const float* gw1  = (const float*)d_in[3];
    const float* gw2  = (const float*)d_in[4];
    const float* tcn  = (const float*)d_in[5];
    const float* bns  = (const float*)d_in[6];
    const float* bnb  = (const float*)d_in[7];
    const float* bnm  = (const float*)d_in[8];
    const float* bnv  = (const float*)d_in[9];
    const float* lns  = (const float*)d_in[10];
    const float* lnb  = (const float*)d_in[11];
    const float* fcw  = (const float*)d_in[12];
    const float* fcb  = (const float*)d_in[13];
    float* out = (float*)d_out;

    // ws: bnc | part | effT0 | effT12 | xg (padded)
    float* bnc  = (float*)d_ws;
    float* part = bnc + 384;
    short* effT0  = (short*)(part + (size_t)B_DIM * 256 * 64);
    short* effT12 = effT0 + 2048;
    float* xg = (float*)(effT12 + 24576);
    const size_t fixed_bytes = 384 * 4 + (size_t)B_DIM * 256 * 64 * 4
                             + 2048 * 2 + 24576 * 2;
    const size_t xg_per_b = (size_t)TP_DIM * 52 * 4;            // 427,648 B

    int cb = B_DIM;
    while (cb > 1 && fixed_bytes + (size_t)cb * xg_per_b > ws_size) cb >>= 1;

    fold_weights_kernel<<<96, 256, 0, stream>>>(gw0, gw1, gw2, tcn,
                                                bns, bnb, bnm, bnv,
                                                effT0, effT12, bnc);

    for (int b0 = 0; b0 < B_DIM; b0 += cb) {
        premix_kernel<<<dim3((TP_DIM + 63) / 64, cb), 256, 0, stream>>>(
            kpts + (size_t)b0 * T_DIM * K_DIM * 3, adj, xg);
        stgcn_mono_kernel<<<dim3(T_DIM / 8, cb), 256, 0, stream>>>(
            xg, adj, effT0, effT12, bnc, part, b0);
    }

    finish_kernel<<<B_DIM, 256, 0, stream>>>(part, lns, lnb, fcw, fcb, out);
}

// Round 21
// 235.525 us; speedup vs baseline: 1.0034x; 1.0034x over previous
//
#include <hip/hip_runtime.h>
#include <hip/hip_fp16.h>
#include <math.h>

#define T_DIM 2048
#define K_DIM 17
#define HID   64
#define B_DIM 32

typedef short s16x8 __attribute__((ext_vector_type(8)));
typedef unsigned u32x2 __attribute__((ext_vector_type(2)));
typedef float f32x4 __attribute__((ext_vector_type(4)));
typedef _Float16 f16x2 __attribute__((ext_vector_type(2)));

__device__ __forceinline__ unsigned pkh(float lo, float hi) {
    return __builtin_bit_cast(unsigned, __builtin_amdgcn_cvt_pkrtz(lo, hi));
}
__device__ __forceinline__ f16x2 u2h(unsigned v) {
    return __builtin_bit_cast(f16x2, v);
}
__device__ __forceinline__ unsigned h2u(f16x2 v) {
    return __builtin_bit_cast(unsigned, v);
}
__device__ __forceinline__ short f2h(float f) {          // cold path
    _Float16 h = (_Float16)f;
    return __builtin_bit_cast(short, h);
}

// COCO skeleton sparsity: column-v nonzeros of adj (incl. self).
static constexpr int NBR_PTR[18] = {0,3,6,9,11,13,17,21,24,27,29,31,34,37,40,43,45,47};
static constexpr int NBR_K[47] = {
    0,1,2,  0,1,3,  0,2,4,  1,3,  2,4,
    5,6,7,11,  5,6,8,12,  5,7,9,  6,8,10,  7,9,  8,10,
    5,11,13,  6,12,14,  11,13,15,  12,14,16,  13,15,  14,16 };
__device__ const int d_NBR_PTR[18] = {0,3,6,9,11,13,17,21,24,27,29,31,34,37,40,43,45,47};
__device__ const int d_NBR_K[47] = {
    0,1,2,  0,1,3,  0,2,4,  1,3,  2,4,
    5,6,7,11,  5,6,8,12,  5,7,9,  6,8,10,  7,9,  8,10,
    5,11,13,  6,12,14,  11,13,15,  12,14,16,  13,15,  14,16 };

// ---------------------------------------------------------------------------
// Fold GCN channel-mix into temporal conv weights (f16).
//   effT0[o][k32]; effT12[blk][o][dt*64+c] for blocks 2,3.
// ---------------------------------------------------------------------------
__global__ void fold_weights_kernel(
    const float* __restrict__ gw0, const float* __restrict__ gw1,
    const float* __restrict__ gw2, const float* __restrict__ tcn,
    const float* __restrict__ bns, const float* __restrict__ bnb,
    const float* __restrict__ bnm, const float* __restrict__ bnv,
    short* __restrict__ effT0, short* __restrict__ effT12,
    float* __restrict__ bnc)
{
    int tid = blockIdx.x * blockDim.x + threadIdx.x;
    int stride = gridDim.x * blockDim.x;
    for (int idx = tid; idx < 2048; idx += stride) {
        int o = idx >> 5, k = idx & 31, dt = k >> 3, cin = k & 7;
        float s = 0.f;
        if (dt < 3 && cin < 3)
            for (int m = 0; m < 64; m++)
                s += gw0[cin * 64 + m] * tcn[(o * 64 + m) * 3 + dt];
        effT0[idx] = f2h(s);
    }
    for (int idx = tid; idx < 24576; idx += stride) {
        int blk = idx / 12288;
        int r = idx - blk * 12288;
        int o = r / 192, k = r - o * 192, dt = k >> 6, c = k & 63;
        const float* gw = blk ? gw2 : gw1;
        const float* tw = tcn + (size_t)(blk + 1) * 64 * 64 * 3;
        float s = 0.f;
        for (int m = 0; m < 64; m++)
            s += gw[c * 64 + m] * tw[(o * 64 + m) * 3 + dt];
        effT12[idx] = f2h(s);
    }
    for (int i = tid; i < 192; i += stride) {
        float inv = bns[i] * rsqrtf(bnv[i] + 1e-5f);
        bnc[i] = inv;
        bnc[192 + i] = bnb[i] - bnm[i] * inv;
    }
}

// ---------------------------------------------------------------------------
// Monolith: premix + all 3 blocks + pool; activations never leave LDS.
// WG = (b, 8 output t's).  In-kernel premix: stage x rows t0-4..t0+11
// (816 floats, coalesced, aliased onto ybuf) -> 272 gather items -> xtg.
// Then: GEMM1(15 tiles, K=32) -> y1 | GEMM2 split 7+6 -> z2 | mix2 + pool +
// block3 premix (in-place) | GEMM3(9, DIL=2) + BN/ReLU + pool | combine.
// LDS 39.9 KB -> 4 WG/CU; (256,4) cap 128 VGPR (no spill; R11 spilled at 5).
// ---------------------------------------------------------------------------
__global__ __launch_bounds__(256, 4) void stgcn_mono_kernel(
    const float* __restrict__ x, const float* __restrict__ adj,
    const short* __restrict__ effT0, const short* __restrict__ effT12,
    const float* __restrict__ bnc, float* __restrict__ part)
{
    __shared__ unsigned adj_h[289];
    __shared__ float adj_s[289];
    __shared__ __align__(16) float xtg[16 * 52];       // 3328 B (aliased later)
    __shared__ __align__(16) short ybuf[238 * 72];     // 34272 B

    float* xs  = (float*)ybuf;           // stage area, dead before GEMM1 writes
    float* prm = (float*)xtg;            // [8][64] pool partials (xtg dead)
    float* pr1 = (float*)xtg + 512;      // [64] GEMM3 pool

    const int tid = threadIdx.x;
    const int b = blockIdx.y;
    const int t0 = blockIdx.x * 8;
    const int lane = tid & 63, wave = tid >> 6;
    const int col = lane & 15, kgrp = lane >> 4;

    for (int i = tid; i < 289; i += 256) {
        float w = adj[i];
        adj_h[i] = pkh(w, w);
        adj_s[i] = w;
    }
    {   // coalesced x stage: rows t = t0-4 .. t0+11 (816 floats), zero OOB
        const int tbase = t0 - 4;
        const int lo_i = (tbase < 0) ? (-tbase) * 51 : 0;
        const int hr = T_DIM - tbase;
        const int hi_i = (hr >= 16) ? 816 : (hr < 0 ? 0 : hr * 51);
        const float* xb = x + ((size_t)b * T_DIM + tbase) * 51;
        for (int i = tid; i < 816; i += 256)
            xs[i] = (i >= lo_i && i < hi_i) ? xb[i] : 0.f;
    }
    s16x8 af1 = *(const s16x8*)(effT0 + (wave * 16 + col) * 32 + kgrp * 8);
    s16x8 af2[6];
    #pragma unroll
    for (int kk = 0; kk < 6; kk++)
        af2[kk] = *(const s16x8*)(effT12 +
            (wave * 16 + col) * 192 + kk * 32 + kgrp * 8);
    __syncthreads();

    // ---- premix: 272 items (row, j) -> xtg[row*52 + j*3 + c] ----
    for (int it = tid; it < 272; it += 256) {
        const int row = (it * 241) >> 12;    // it/17 for it<272
        const int j = it - row * 17;
        const float* xp = &xs[row * 51];
        float a0 = 0.f, a1 = 0.f, a2 = 0.f;
        const int p0 = d_NBR_PTR[j], p1 = d_NBR_PTR[j + 1];
        for (int e = p0; e < p1; e++) {
            int k = d_NBR_K[e];
            float w = adj_s[k * 17 + j];
            a0 += w * xp[k * 3 + 0];
            a1 += w * xp[k * 3 + 1];
            a2 += w * xp[k * 3 + 2];
        }
        xtg[row * 52 + j * 3 + 0] = a0;
        xtg[row * 52 + j * 3 + 1] = a1;
        xtg[row * 52 + j * 3 + 2] = a2;
    }
    __syncthreads();

    // ---- GEMM1: 238 rows (15 tiles), K=32; BN+ReLU epilogue -> y1 ----
    {
        f32x4 inv4 = *(const f32x4*)&bnc[wave * 16 + kgrp * 4];
        f32x4 sh4  = *(const f32x4*)&bnc[192 + wave * 16 + kgrp * 4];
        for (int tile = 0; tile < 15; tile++) {
            const int r = tile * 16 + col;
            const int me = r < 238 ? r : 237;
            const int s = (me * 241) >> 12;     // me/17 for me<256
            const int j = me - s * 17;
            int4 bz = {0, 0, 0, 0};
            if (kgrp < 3) {                      // dt = kgrp; x time = t0-4+s+dt
                const float* xp = &xtg[(s + kgrp) * 52 + j * 3];
                bz.x = (int)pkh(xp[0], xp[1]);
                bz.y = (int)pkh(xp[2], 0.f);
            }
            s16x8 bfr = __builtin_bit_cast(s16x8, bz);
            f32x4 acc = __builtin_amdgcn_mfma_f32_16x16x32_f16(
                af1, bfr, (f32x4){0.f, 0.f, 0.f, 0.f}, 0, 0, 0);
            const int t = t0 - 3 + s;
            const bool valid = (t >= 0) && (t < T_DIM);
            if (r < 238) {
                float v0 = valid ? fmaxf(acc[0] * inv4[0] + sh4[0], 0.f) : 0.f;
                float v1 = valid ? fmaxf(acc[1] * inv4[1] + sh4[1], 0.f) : 0.f;
                float v2 = valid ? fmaxf(acc[2] * inv4[2] + sh4[2], 0.f) : 0.f;
                float v3 = valid ? fmaxf(acc[3] * inv4[3] + sh4[3], 0.f) : 0.f;
                u32x2 st; st[0] = pkh(v0, v1); st[1] = pkh(v2, v3);
                *(u32x2*)&ybuf[r * 72 + wave * 16 + kgrp * 4] = st;
            }
        }
    }
    __syncthreads();

    // ---- residual preload: y1 rows (tl+1)*17+v for items (tl, o-pair) ----
    const int tl0 = tid >> 5, oq = tid & 31, o0 = oq * 2;
    unsigned rv[2][17];
    #pragma unroll
    for (int v = 0; v < 17; v++)
        rv[0][v] = *(const unsigned*)&ybuf[((tl0 + 1) * 17 + v) * 72 + o0];
    if (tid < 128) {
        #pragma unroll
        for (int v = 0; v < 17; v++)
            rv[1][v] = *(const unsigned*)&ybuf[((tl0 + 9) * 17 + v) * 72 + o0];
    }

    // ---- GEMM2 pass1: tiles 0..6 (rows 0..111; reads ybuf rows 0..145) ----
    f32x4 accA[7];
    #pragma unroll
    for (int t2 = 0; t2 < 7; t2++) accA[t2] = (f32x4){0.f, 0.f, 0.f, 0.f};
    #pragma unroll
    for (int kk = 0; kk < 6; kk++) {
        #pragma unroll
        for (int t2 = 0; t2 < 7; t2++) {
            const int r = t2 * 16 + col;
            s16x8 bfr = *(const s16x8*)&ybuf[
                (r + 17 * (kk >> 1)) * 72 + (kk & 1) * 32 + kgrp * 8];
            accA[t2] = __builtin_amdgcn_mfma_f32_16x16x32_f16(
                af2[kk], bfr, accA[t2], 0, 0, 0);
        }
    }
    __syncthreads();

    // ---- z2 write pass1 (rows 0..111) + GEMM2 pass2 (reads rows 112..237) ----
    #pragma unroll
    for (int t2 = 0; t2 < 7; t2++) {
        const int r = t2 * 16 + col;
        u32x2 st;
        st[0] = pkh(accA[t2][0], accA[t2][1]);
        st[1] = pkh(accA[t2][2], accA[t2][3]);
        *(u32x2*)&ybuf[r * 72 + wave * 16 + kgrp * 4] = st;
    }
    f32x4 accB[6];
    #pragma unroll
    for (int t2 = 0; t2 < 6; t2++) accB[t2] = (f32x4){0.f, 0.f, 0.f, 0.f};
    #pragma unroll
    for (int kk = 0; kk < 6; kk++) {
        #pragma unroll
        for (int t2 = 0; t2 < 6; t2++) {
            const int r = (t2 + 7) * 16 + col;
            const int me = r < 204 ? r : 203;
            s16x8 bfr = *(const s16x8*)&ybuf[
                (me + 17 * (kk >> 1)) * 72 + (kk & 1) * 32 + kgrp * 8];
            accB[t2] = __builtin_amdgcn_mfma_f32_16x16x32_f16(
                af2[kk], bfr, accB[t2], 0, 0, 0);
        }
    }
    __syncthreads();

    // ---- z2 write pass2 (rows 112..203) ----
    #pragma unroll
    for (int t2 = 0; t2 < 6; t2++) {
        const int r = (t2 + 7) * 16 + col;
        if (r < 204) {
            u32x2 st;
            st[0] = pkh(accB[t2][0], accB[t2][1]);
            st[1] = pkh(accB[t2][2], accB[t2][3]);
            *(u32x2*)&ybuf[r * 72 + wave * 16 + kgrp * 4] = st;
        }
    }
    __syncthreads();

    // ---- mix2 + pool + block3 premix, in-place (rows tl*17+*) ----
    {
        const f16x2 inv2 = u2h(pkh(bnc[64 + o0], bnc[64 + o0 + 1]));
        const f16x2 sh2  = u2h(pkh(bnc[256 + o0], bnc[256 + o0 + 1]));
        const f16x2 zero = u2h(0u);
        #pragma unroll
        for (int it = 0; it < 2; it++) {
            const int tl = tl0 + it * 8;
            if (it == 1 && tid >= 128) break;     // tl would exceed 11
            const int t = t0 - 2 + tl;
            const bool valid = (t >= 0) && (t < T_DIM);
            f16x2 zk[17];
            #pragma unroll
            for (int k = 0; k < 17; k++)
                zk[k] = u2h(*(const unsigned*)&ybuf[(tl * 17 + k) * 72 + o0]);
            f16x2 y2v[17];
            f16x2 pool = zero;
            #pragma unroll
            for (int v = 0; v < 17; v++) {
                f16x2 g = zero;
                #pragma unroll
                for (int e = NBR_PTR[v]; e < NBR_PTR[v + 1]; e++) {
                    int k = NBR_K[e];
                    g = u2h(adj_h[k * 17 + v]) * zk[k] + g;
                }
                f16x2 val = __builtin_elementwise_max(g * inv2 + sh2, zero);
                val = val + u2h(rv[it][v]);
                if (!valid) val = zero;
                y2v[v] = val;
                pool = pool + val;
            }
            if (tl >= 2 && tl <= 9) {
                prm[(tl - 2) * 64 + o0]     = (float)pool[0];
                prm[(tl - 2) * 64 + o0 + 1] = (float)pool[1];
            }
            #pragma unroll
            for (int j = 0; j < 17; j++) {
                f16x2 gg = zero;
                #pragma unroll
                for (int e = NBR_PTR[j]; e < NBR_PTR[j + 1]; e++) {
                    int k = NBR_K[e];
                    gg = u2h(adj_h[k * 17 + j]) * y2v[k] + gg;
                }
                *(unsigned*)&ybuf[(tl * 17 + j) * 72 + o0] = h2u(gg);
            }
        }
    }
    __syncthreads();

    // ---- GEMM3: 136 rows (9 tiles), K=192, DIL=2 + BN/ReLU + pool ----
    {
        s16x8 af3[6];
        #pragma unroll
        for (int kk = 0; kk < 6; kk++)
            af3[kk] = *(const s16x8*)(effT12 + 12288 +
                (wave * 16 + col) * 192 + kk * 32 + kgrp * 8);
        const f32x4 inv4 = *(const f32x4*)&bnc[128 + wave * 16 + kgrp * 4];
        const f32x4 sh4  = *(const f32x4*)&bnc[320 + wave * 16 + kgrp * 4];
        float psum[4] = {0.f, 0.f, 0.f, 0.f};
        for (int t3 = 0; t3 < 9; t3++) {
            const int r = t3 * 16 + col;
            const int me = r < 136 ? r : 135;
            f32x4 acc = (f32x4){0.f, 0.f, 0.f, 0.f};
            #pragma unroll
            for (int kk = 0; kk < 6; kk++) {
                s16x8 bfr = *(const s16x8*)&ybuf[
                    (me + 34 * (kk >> 1)) * 72 + (kk & 1) * 32 + kgrp * 8];
                acc = __builtin_amdgcn_mfma_f32_16x16x32_f16(
                    af3[kk], bfr, acc, 0, 0, 0);
            }
            if (r < 136) {
                psum[0] += fmaxf(acc[0] * inv4[0] + sh4[0], 0.f);
                psum[1] += fmaxf(acc[1] * inv4[1] + sh4[1], 0.f);
                psum[2] += fmaxf(acc[2] * inv4[2] + sh4[2], 0.f);
                psum[3] += fmaxf(acc[3] * inv4[3] + sh4[3], 0.f);
            }
        }
        #pragma unroll
        for (int off = 1; off <= 8; off <<= 1) {
            psum[0] += __shfl_xor(psum[0], off);
            psum[1] += __shfl_xor(psum[1], off);
            psum[2] += __shfl_xor(psum[2], off);
            psum[3] += __shfl_xor(psum[3], off);
        }
        if (col == 0)
            *(f32x4*)&pr1[wave * 16 + kgrp * 4] =
                (f32x4){psum[0], psum[1], psum[2], psum[3]};
    }
    __syncthreads();
    if (tid < 64) {
        float s = pr1[tid];
        #pragma unroll
        for (int i = 0; i < 8; i++) s += prm[i * 64 + tid];
        part[((size_t)b * 256 + blockIdx.x) * 64 + tid] = s;
    }
}

// ---------------------------------------------------------------------------
// Sum 256 partials per (b,c) with 256 threads, mean, LayerNorm, FC.
// ---------------------------------------------------------------------------
__global__ __launch_bounds__(256) void finish_kernel(
    const float* __restrict__ part, const float* __restrict__ ln_s,
    const float* __restrict__ ln_b, const float* __restrict__ fc_w,
    const float* __restrict__ fc_b, float* __restrict__ out)
{
    __shared__ float red[4][64];
    __shared__ float ns[64];
    const int b = blockIdx.x;
    const int g = threadIdx.x >> 6, c = threadIdx.x & 63;
    float s = 0.f;
    for (int j = 0; j < 64; j++)
        s += part[((size_t)b * 256 + g * 64 + j) * 64 + c];
    red[g][c] = s;
    __syncthreads();
    if (threadIdx.x < 64) {
        float feat = (red[0][c] + red[1][c] + red[2][c] + red[3][c])
                   / (float)(T_DIM * K_DIM);
        float m = feat;
        #pragma unroll
        for (int off = 32; off > 0; off >>= 1) m += __shfl_down(m, off);
        m = __shfl(m, 0) / 64.f;
        float d = feat - m;
        float v = d * d;
        #pragma unroll
        for (int off = 32; off > 0; off >>= 1) v += __shfl_down(v, off);
        v = __shfl(v, 0) / 64.f;
        ns[c] = d * rsqrtf(v + 1e-5f) * ln_s[c] + ln_b[c];
    }
    __syncthreads();
    if (threadIdx.x < 10) {
        float o = fc_b[threadIdx.x];
        for (int i = 0; i < 64; i++) o += ns[i] * fc_w[i * 10 + threadIdx.x];
        out[b * 10 + threadIdx.x] = o;
    }
}

// ---------------------------------------------------------------------------
extern "C" void kernel_launch(void* const* d_in, const int* in_sizes, int n_in,
                              void* d_out, int out_size, void* d_ws, size_t ws_size,
                              hipStream_t stream)
{
    const float* kpts = (const float*)d_in[0];
    const float* adj  = (const float*)d_in[1];
    const float* gw0  = (const float*)d_in[2];
    const float* gw1  = (const float*)d_in[3];
    const float* gw2  = (const float*)d_in[4];
    const float* tcn  = (const float*)d_in[5];
    const float* bns  = (const float*)d_in[6];
    const float* bnb  = (const float*)d_in[7];
    const float* bnm  = (const float*)d_in[8];
    const float* bnv  = (const float*)d_in[9];
    const float* lns  = (const float*)d_in[10];
    const float* lnb  = (const float*)d_in[11];
    const float* fcw  = (const float*)d_in[12];
    const float* fcb  = (const float*)d_in[13];
    float* out = (float*)d_out;

    // ws: bnc(384 f) | part(32*256*64 f) | effT0(2048 s) | effT12(24576 s)
    // total ~2.2 MB
    float* bnc  = (float*)d_ws;
    float* part = bnc + 384;
    short* effT0  = (short*)(part + (size_t)B_DIM * 256 * 64);
    short* effT12 = effT0 + 2048;

    fold_weights_kernel<<<96, 256, 0, stream>>>(gw0, gw1, gw2, tcn,
                                                bns, bnb, bnm, bnv,
                                                effT0, effT12, bnc);

    stgcn_mono_kernel<<<dim3(T_DIM / 8, B_DIM), 256, 0, stream>>>(
        kpts, adj, effT0, effT12, bnc, part);

    finish_kernel<<<B_DIM, 256, 0, stream>>>(part, lns, lnb, fcw, fcb, out);
}